// Round 9
// baseline (250.356 us; speedup 1.0000x reference)
//
#include <hip/hip_runtime.h>
#include <stdint.h>
#include <stddef.h>

// Multi-head attention: x@w_qkv+b -> heads -> softmax(QK^T/sqrt(D))V -> @w_proj+b
// B=8 N=1024 C=1024 H=16 D=64. bf16 MFMA, fp32 accum, fp32 softmax (log2 domain).
// 4 kernels: prep (weight transposes), gemm1 (fp32-A fused QKV, V written transposed),
// attn (32x32x16 swapped MFMA), gemm2 (projection).

#define DEVI __device__ __forceinline__

typedef float f32x4 __attribute__((ext_vector_type(4)));
typedef float f32x16 __attribute__((ext_vector_type(16)));
typedef __bf16 bf16x8 __attribute__((ext_vector_type(8)));
typedef unsigned short u16x8 __attribute__((ext_vector_type(8)));
typedef unsigned short u16x4 __attribute__((ext_vector_type(4)));
typedef unsigned int u32;
typedef unsigned int u32x4 __attribute__((ext_vector_type(4)));

static constexpr int M1 = 8192;   // B*N rows

DEVI unsigned short f2bf(float f) {
  uint32_t u = __builtin_bit_cast(uint32_t, f);
  u += 0x7FFFu + ((u >> 16) & 1u);   // RNE
  return (unsigned short)(u >> 16);
}

DEVI float fexp2(float x) {
  float r;
  asm("v_exp_f32 %0, %1" : "=v"(r) : "v"(x));
  return r;
}

DEVI u32 cvtpk(float lo, float hi) {
  u32 r;
  asm("v_cvt_pk_bf16_f32 %0, %1, %2" : "=v"(r) : "v"(lo), "v"(hi));
  return r;
}

DEVI void plswap(u32& a, u32& b) {
  asm("v_permlane32_swap_b32 %0, %1" : "+v"(a), "+v"(b));
}

DEVI void gll16(const unsigned short* g, unsigned short* lds) {
  __builtin_amdgcn_global_load_lds(
      (const __attribute__((address_space(1))) void*)g,
      (__attribute__((address_space(3))) void*)lds, 16, 0, 0);
}

DEVI bf16x8 lds_frag(const unsigned short* p) {
  return __builtin_bit_cast(bf16x8, *(const u16x8*)p);
}

// ---------------- prep: transpose+convert both weight matrices (one launch) ----------------
// bx<96: w_qkv [1024][3072] -> wqkvT [3072][1024];  bx>=96: w_proj -> wprojT [1024][1024]
__global__ void k_prep(const float* __restrict__ wqkv, const float* __restrict__ wproj,
                       unsigned short* __restrict__ wqkvT, unsigned short* __restrict__ wprojT) {
  __shared__ float tile[32][33];
  const int bx = blockIdx.x;
  const float* in = (bx < 96) ? wqkv : wproj;
  unsigned short* out = (bx < 96) ? wqkvT : wprojT;
  const int Cc = (bx < 96) ? 3072 : 1024;
  const int c0 = ((bx < 96) ? bx : bx - 96) * 32, r0 = blockIdx.y * 32;
  const int tx = threadIdx.x, ty = threadIdx.y;   // blockDim (32,8)
#pragma unroll
  for (int j = 0; j < 32; j += 8)
    tile[ty + j][tx] = in[(size_t)(r0 + ty + j) * Cc + c0 + tx];
  __syncthreads();
#pragma unroll
  for (int j = 0; j < 32; j += 8)
    out[(size_t)(c0 + ty + j) * 1024 + r0 + tx] = f2bf(tile[tx][ty + j]);
}

// ---------------- GEMM1: QKV = x(fp32) @ w_qkvT^T + b ----------------
// 128x128 tile, BK=32, 4 waves (m97 structure). A staged from fp32 via T14 split:
// issue float4 loads early || gll16 B; convert+ds_write after MFMA. Dest-side
// chunk swizzle dst = r*4 + (s ^ ((r>>1)&3)) (read side unchanged from m97 form).
// Epilogue: Q (prescaled log2e/8) [B,H,N,D], K [B,H,N,D], V transposed [B,H,D,N].
__global__ __launch_bounds__(256, 2)
void k_gemm1(const float* __restrict__ X,
             const unsigned short* __restrict__ Bt,
             const float* __restrict__ bias,
             unsigned short* __restrict__ Qp,
             unsigned short* __restrict__ Kp,
             unsigned short* __restrict__ Vtp) {
  constexpr int K = 1024, NK = K / 32;
  __shared__ unsigned short As[2][128 * 32];
  __shared__ unsigned short Bs[2][128 * 32];

  const int tid = threadIdx.x;
  const int w = tid >> 6, l = tid & 63;
  const int ln = l & 15, kg = l >> 4;
  const int wr = w >> 1, wc = w & 1;

  const int rt = blockIdx.x % (M1 / 128);
  const int ct = blockIdx.x / (M1 / 128);
  const int row0 = rt * 128, col0 = ct * 128;

  f32x4 acc[4][4] = {};

  const float* Ag = X + (size_t)row0 * K;
  const unsigned short* Bg = Bt + (size_t)col0 * K;

  // per-thread A-chunk coordinates (2 chunks: j=0,1)
  int cr[2], cs[2], cd[2];
#pragma unroll
  for (int j = 0; j < 2; j++) {
    int c = j * 256 + w * 64 + l;
    cr[j] = c >> 2; cs[j] = c & 3;
    cd[j] = cr[j] * 4 + (cs[j] ^ ((cr[j] >> 1) & 3));
  }

  auto loadA = [&](int kt, float4* a0, float4* a1) {
#pragma unroll
    for (int j = 0; j < 2; j++) {
      const float* src = Ag + (size_t)cr[j] * K + kt * 32 + cs[j] * 8;
      a0[j] = *(const float4*)src;
      a1[j] = *(const float4*)(src + 4);
    }
  };
  auto writeA = [&](int buf, const float4* a0, const float4* a1) {
#pragma unroll
    for (int j = 0; j < 2; j++) {
      u16x8 p = { f2bf(a0[j].x), f2bf(a0[j].y), f2bf(a0[j].z), f2bf(a0[j].w),
                  f2bf(a1[j].x), f2bf(a1[j].y), f2bf(a1[j].z), f2bf(a1[j].w) };
      *(u16x8*)&As[buf][cd[j] * 8] = p;
    }
  };
  auto stageB = [&](int buf, int kt) {
    const unsigned short* gb = Bg + kt * 32;
#pragma unroll
    for (int j = 0; j < 2; j++) {
      int c = j * 256 + w * 64 + l;
      int r = c >> 2, s = c & 3;
      int ss = s ^ ((r >> 1) & 3);
      gll16(gb + (size_t)r * K + ss * 8, &Bs[buf][(j * 256 + w * 64) * 8]);
    }
  };

  // prologue (serial, once)
  {
    float4 a0[2], a1[2];
    loadA(0, a0, a1);
    writeA(0, a0, a1);
    stageB(0, 0);
  }
  __syncthreads();

  int buf = 0;
  for (int kt = 0; kt < NK; kt++) {
    float4 a0[2], a1[2];
    if (kt + 1 < NK) {
      loadA(kt + 1, a0, a1);          // issue early (hides under MFMA)
      stageB(buf ^ 1, kt + 1);
    }
    __builtin_amdgcn_sched_barrier(0); // keep load issue above the compute block

    bf16x8 af[4], bfr[4];
#pragma unroll
    for (int m = 0; m < 4; m++) {
      int r = wr * 64 + m * 16 + ln;
      int sl = kg ^ ((r >> 1) & 3);
      af[m] = lds_frag(&As[buf][r * 32 + sl * 8]);
    }
#pragma unroll
    for (int n = 0; n < 4; n++) {
      int r = wc * 64 + n * 16 + ln;
      int sl = kg ^ ((r >> 1) & 3);
      bfr[n] = lds_frag(&Bs[buf][r * 32 + sl * 8]);
    }
    __builtin_amdgcn_s_setprio(1);
#pragma unroll
    for (int m = 0; m < 4; m++)
#pragma unroll
      for (int n = 0; n < 4; n++)
        acc[m][n] = __builtin_amdgcn_mfma_f32_16x16x32_bf16(af[m], bfr[n], acc[m][n], 0, 0, 0);
    __builtin_amdgcn_s_setprio(0);

    if (kt + 1 < NK) writeA(buf ^ 1, a0, a1);   // write late (waits on loads here)
    __syncthreads();
    buf ^= 1;
  }

  constexpr float QS = 0.18033688011112042f;   // log2(e)/8
  float bv[4];
#pragma unroll
  for (int n = 0; n < 4; n++) bv[n] = bias[col0 + wc * 64 + n * 16 + ln];

  const int three = col0 >> 10;               // which tensor (Q/K/V)
  const int h = ((col0 & 1023) >> 6) + wc;    // head (64 cols per wave = one head)
  if (three < 2) {
    unsigned short* tgt = (three == 0) ? Qp : Kp;
    const float sc = (three == 0) ? QS : 1.f;
#pragma unroll
    for (int m = 0; m < 4; m++)
#pragma unroll
      for (int r = 0; r < 4; r++) {
        int row = row0 + wr * 64 + m * 16 + kg * 4 + r;
        int bb = row >> 10, nn = row & 1023;
        size_t base = ((size_t)(bb * 16 + h) * 1024 + nn) * 64;
#pragma unroll
        for (int n = 0; n < 4; n++)
          tgt[base + n * 16 + ln] = f2bf((acc[m][n][r] + bv[n]) * sc);
      }
  } else {
    // V transposed -> Vt[bh][d][n]; each 128B line fully dirtied by this wave's
    // temporally-adjacent stores -> L2 write-combines (verified round 8: WRITE ~49MB).
#pragma unroll
    for (int m = 0; m < 4; m++)
#pragma unroll
      for (int r = 0; r < 4; r++) {
        int row = row0 + wr * 64 + m * 16 + kg * 4 + r;
        int bb = row >> 10, nn = row & 1023;
        size_t dbase = (size_t)(bb * 16 + h) * 64;
#pragma unroll
        for (int n = 0; n < 4; n++)
          Vtp[(dbase + n * 16 + ln) * 1024 + nn] = f2bf(acc[m][n][r] + bv[n]);
      }
  }
}

// ---------------- GEMM2: out = AO @ w_projT^T + b (fp32 out) ----------------
__global__ __launch_bounds__(256, 2)
void k_gemm2(const unsigned short* __restrict__ A,
             const unsigned short* __restrict__ Bt,
             const float* __restrict__ bias,
             float* __restrict__ Out) {
  constexpr int K = 1024, NK = K / 32;
  __shared__ unsigned short As[2][128 * 32];
  __shared__ unsigned short Bs[2][128 * 32];

  const int tid = threadIdx.x;
  const int w = tid >> 6, l = tid & 63;
  const int ln = l & 15, kg = l >> 4;
  const int wr = w >> 1, wc = w & 1;

  const int rt = blockIdx.x % (M1 / 128);
  const int ct = blockIdx.x / (M1 / 128);
  const int row0 = rt * 128, col0 = ct * 128;

  f32x4 acc[4][4] = {};

  const unsigned short* Ag = A + (size_t)row0 * K;
  const unsigned short* Bg = Bt + (size_t)col0 * K;

  auto stage = [&](int buf, int kt) {
    const unsigned short* ga = Ag + kt * 32;
    const unsigned short* gb = Bg + kt * 32;
#pragma unroll
    for (int j = 0; j < 2; j++) {
      int c = j * 256 + w * 64 + l;
      int r = c >> 2, s = c & 3;
      int ss = s ^ ((r >> 1) & 3);
      gll16(ga + (size_t)r * K + ss * 8, &As[buf][(j * 256 + w * 64) * 8]);
      gll16(gb + (size_t)r * K + ss * 8, &Bs[buf][(j * 256 + w * 64) * 8]);
    }
  };

  stage(0, 0);
  __syncthreads();

  int buf = 0;
  for (int kt = 0; kt < NK; kt++) {
    if (kt + 1 < NK) stage(buf ^ 1, kt + 1);

    bf16x8 af[4], bfr[4];
#pragma unroll
    for (int m = 0; m < 4; m++) {
      int r = wr * 64 + m * 16 + ln;
      int sl = kg ^ ((r >> 1) & 3);
      af[m] = lds_frag(&As[buf][r * 32 + sl * 8]);
    }
#pragma unroll
    for (int n = 0; n < 4; n++) {
      int r = wc * 64 + n * 16 + ln;
      int sl = kg ^ ((r >> 1) & 3);
      bfr[n] = lds_frag(&Bs[buf][r * 32 + sl * 8]);
    }
    __builtin_amdgcn_s_setprio(1);
#pragma unroll
    for (int m = 0; m < 4; m++)
#pragma unroll
      for (int n = 0; n < 4; n++)
        acc[m][n] = __builtin_amdgcn_mfma_f32_16x16x32_bf16(af[m], bfr[n], acc[m][n], 0, 0, 0);
    __builtin_amdgcn_s_setprio(0);

    __syncthreads();
    buf ^= 1;
  }

  float bv[4];
#pragma unroll
  for (int n = 0; n < 4; n++) bv[n] = bias[col0 + wc * 64 + n * 16 + ln];
#pragma unroll
  for (int m = 0; m < 4; m++)
#pragma unroll
    for (int r = 0; r < 4; r++) {
      int row = row0 + wr * 64 + m * 16 + kg * 4 + r;
#pragma unroll
      for (int n = 0; n < 4; n++)
        Out[(size_t)row * 1024 + col0 + wc * 64 + n * 16 + ln] = acc[m][n][r] + bv[n];
    }
}

// ---------------- flash attention, 32x32x16 swapped MFMA ----------------
// grid (128 bh, 8 q-tiles); 4 waves x 32 q-rows, KVBLK=64, LDS double-buffered.
__global__ __launch_bounds__(256, 4)
void k_attn(const unsigned short* __restrict__ Qg, const unsigned short* __restrict__ Kg,
            const unsigned short* __restrict__ Vtg, unsigned short* __restrict__ AO) {
  __shared__ unsigned short Ks[2][64 * 64];
  __shared__ unsigned short Vs[2][64 * 64];

  const int tid = threadIdx.x;
  const int w = tid >> 6, l = tid & 63;
  const int lq = l & 31, b = l >> 5;

  const int bh = blockIdx.x;
  const int qt = blockIdx.y;
  const int qbase = qt * 128 + w * 32;

  bf16x8 qf[4];
#pragma unroll
  for (int kk = 0; kk < 4; kk++) {
    size_t off = ((size_t)bh * 1024 + qbase + lq) * 64 + kk * 16 + b * 8;
    qf[kk] = __builtin_bit_cast(bf16x8, *(const u16x8*)(Qg + off));
  }

  f32x16 acc[2] = {};
  float mrun = -1e30f, lrun = 0.f;

  const unsigned short* Kbh = Kg + (size_t)bh * 1024 * 64;
  const unsigned short* Vbh = Vtg + (size_t)bh * 64 * 1024;

  auto stage = [&](int buf, int t) {
#pragma unroll
    for (int j = 0; j < 2; j++) {
      int c = j * 256 + w * 64 + l;
      int r = c >> 3, s = c & 7;
      int ss = s ^ (r & 7);
      gll16(Kbh + (size_t)(t * 64 + r) * 64 + ss * 8, &Ks[buf][(j * 256 + w * 64) * 8]);
      gll16(Vbh + (size_t)r * 1024 + t * 64 + ss * 8, &Vs[buf][(j * 256 + w * 64) * 8]);
    }
  };

  stage(0, 0);
  __syncthreads();

  int buf = 0;
  for (int t = 0; t < 16; t++) {
    if (t + 1 < 16) stage(buf ^ 1, t + 1);

    f32x16 s[2];
    __builtin_amdgcn_s_setprio(1);
#pragma unroll
    for (int kb = 0; kb < 2; kb++) {
      f32x16 z = {};
#pragma unroll
      for (int kk = 0; kk < 4; kk++) {
        int row = kb * 32 + lq;
        int ss = (kk * 2 + b) ^ (row & 7);
        bf16x8 kf = lds_frag(&Ks[buf][row * 64 + ss * 8]);
        z = __builtin_amdgcn_mfma_f32_32x32x16_bf16(kf, qf[kk], z, 0, 0, 0);
      }
      s[kb] = z;
    }
    __builtin_amdgcn_s_setprio(0);

    float tm = s[0][0];
#pragma unroll
    for (int kb = 0; kb < 2; kb++)
#pragma unroll
      for (int r = 0; r < 16; r++) tm = fmaxf(tm, s[kb][r]);
    tm = fmaxf(tm, __shfl_xor(tm, 32));

    if (!__all(tm <= mrun + 8.f)) {
      float mnew = fmaxf(mrun, tm);
      float al = fexp2(mrun - mnew);
      mrun = mnew;
      lrun *= al;
#pragma unroll
      for (int r = 0; r < 16; r++) {
        float aq = __shfl(al, (r & 3) + 8 * (r >> 2) + 4 * b);
        acc[0][r] *= aq;
        acc[1][r] *= aq;
      }
    }

    float rs = 0.f;
#pragma unroll
    for (int kb = 0; kb < 2; kb++)
#pragma unroll
      for (int r = 0; r < 16; r++) {
        float pv = fexp2(s[kb][r] - mrun);
        s[kb][r] = pv;
        rs += pv;
      }
    rs += __shfl_xor(rs, 32);
    lrun += rs;

    bf16x8 pa[4];
#pragma unroll
    for (int kb = 0; kb < 2; kb++) {
      u32 pk[4][2];
#pragma unroll
      for (int t4 = 0; t4 < 4; t4++) {
        pk[t4][0] = cvtpk(s[kb][t4 * 4 + 0], s[kb][t4 * 4 + 1]);
        pk[t4][1] = cvtpk(s[kb][t4 * 4 + 2], s[kb][t4 * 4 + 3]);
      }
#pragma unroll
      for (int sh = 0; sh < 2; sh++) {
        u32 a0 = pk[2 * sh][0], b0 = pk[2 * sh + 1][0];
        plswap(a0, b0);
        u32 a1 = pk[2 * sh][1], b1 = pk[2 * sh + 1][1];
        plswap(a1, b1);
        u32x4 fr = { a0, a1, b0, b1 };
        pa[kb * 2 + sh] = __builtin_bit_cast(bf16x8, fr);
      }
    }

    __builtin_amdgcn_s_setprio(1);
#pragma unroll
    for (int n = 0; n < 2; n++) {
#pragma unroll
      for (int st = 0; st < 4; st++) {
        int row = n * 32 + lq;
        int ss = (st * 2 + b) ^ (row & 7);
        bf16x8 vb = lds_frag(&Vs[buf][row * 64 + ss * 8]);
        acc[n] = __builtin_amdgcn_mfma_f32_32x32x16_bf16(pa[st], vb, acc[n], 0, 0, 0);
      }
    }
    __builtin_amdgcn_s_setprio(0);

    __syncthreads();
    buf ^= 1;
  }

  const int bb = bh >> 4, h = bh & 15;
  float linv = 1.f / lrun;
#pragma unroll
  for (int r = 0; r < 16; r++) {
    float lq_r = __shfl(linv, (r & 3) + 8 * (r >> 2) + 4 * b);
    int row = qbase + (r & 3) + 8 * (r >> 2) + 4 * b;
    size_t base = ((size_t)(bb * 1024 + row)) * 1024 + h * 64;
#pragma unroll
    for (int n = 0; n < 2; n++)
      AO[base + n * 32 + lq] = f2bf(acc[n][r] * lq_r);
  }
}

// ---------------- launch ----------------
extern "C" void kernel_launch(void* const* d_in, const int* in_sizes, int n_in,
                              void* d_out, int out_size, void* d_ws, size_t ws_size,
                              hipStream_t stream) {
  const float* x      = (const float*)d_in[0];
  const float* w_qkv  = (const float*)d_in[1];
  const float* b_qkv  = (const float*)d_in[2];
  const float* w_proj = (const float*)d_in[3];
  const float* b_proj = (const float*)d_in[4];
  float* out = (float*)d_out;

  constexpr size_t SZ_WQ  = (size_t)3072 * 1024 * 2;
  constexpr size_t SZ_WP  = (size_t)1024 * 1024 * 2;
  constexpr size_t SZ_QKV = (size_t)8 * 16 * 1024 * 64 * 2;  // 16.78 MB each
  char* ws = (char*)d_ws;
  unsigned short* wqkvT  = (unsigned short*)(ws);
  unsigned short* wprojT = (unsigned short*)(ws + SZ_WQ);
  unsigned short* Qb     = (unsigned short*)(ws + SZ_WQ + SZ_WP);
  unsigned short* Kb     = (unsigned short*)(ws + SZ_WQ + SZ_WP + SZ_QKV);
  unsigned short* Vtb    = (unsigned short*)(ws + SZ_WQ + SZ_WP + 2 * SZ_QKV);
  unsigned short* AOb    = (unsigned short*)(ws + SZ_WQ + SZ_WP + 3 * SZ_QKV);
  size_t needed = SZ_WQ + SZ_WP + 4 * SZ_QKV;   // ~75.5 MB
  if (ws_size < needed) return;

  // 1) weight transposes (one launch)
  k_prep<<<dim3(128, 32), dim3(32, 8), 0, stream>>>(w_qkv, w_proj, wqkvT, wprojT);
  // 2) QKV GEMM (A = fp32 x, fused convert) -> Q(scaled), K [B,H,N,D], Vt [B,H,D,N]
  k_gemm1<<<64 * 24, 256, 0, stream>>>(x, wqkvT, b_qkv, Qb, Kb, Vtb);
  // 3) flash attention -> AO
  k_attn<<<dim3(128, 8), 256, 0, stream>>>(Qb, Kb, Vtb, AOb);
  // 4) projection -> out fp32
  k_gemm2<<<64 * 8, 256, 0, stream>>>(AOb, wprojT, b_proj, out);
}

// Round 10
// 237.884 us; speedup vs baseline: 1.0524x; 1.0524x over previous
//
#include <hip/hip_runtime.h>
#include <stdint.h>
#include <stddef.h>

// Multi-head attention: x@w_qkv+b -> heads -> softmax(QK^T/sqrt(D))V -> @w_proj+b
// B=8 N=1024 C=1024 H=16 D=64. bf16 MFMA, fp32 accum, fp32 softmax (log2 domain).
// 4 kernels: prep (x convert + both weight transposes), gemm1 (m97 128x128, V
// written transposed), attn (32x32x16 swapped MFMA), gemm2 (projection).

#define DEVI __device__ __forceinline__

typedef float f32x4 __attribute__((ext_vector_type(4)));
typedef float f32x16 __attribute__((ext_vector_type(16)));
typedef __bf16 bf16x8 __attribute__((ext_vector_type(8)));
typedef unsigned short u16x8 __attribute__((ext_vector_type(8)));
typedef unsigned short u16x4 __attribute__((ext_vector_type(4)));
typedef unsigned int u32;
typedef unsigned int u32x4 __attribute__((ext_vector_type(4)));

static constexpr int M1 = 8192;   // B*N rows

DEVI unsigned short f2bf(float f) {
  uint32_t u = __builtin_bit_cast(uint32_t, f);
  u += 0x7FFFu + ((u >> 16) & 1u);   // RNE
  return (unsigned short)(u >> 16);
}

DEVI float fexp2(float x) {
  float r;
  asm("v_exp_f32 %0, %1" : "=v"(r) : "v"(x));
  return r;
}

DEVI u32 cvtpk(float lo, float hi) {
  u32 r;
  asm("v_cvt_pk_bf16_f32 %0, %1, %2" : "=v"(r) : "v"(lo), "v"(hi));
  return r;
}

DEVI void plswap(u32& a, u32& b) {
  asm("v_permlane32_swap_b32 %0, %1" : "+v"(a), "+v"(b));
}

DEVI void gll16(const unsigned short* g, unsigned short* lds) {
  __builtin_amdgcn_global_load_lds(
      (const __attribute__((address_space(1))) void*)g,
      (__attribute__((address_space(3))) void*)lds, 16, 0, 0);
}

DEVI bf16x8 lds_frag(const unsigned short* p) {
  return __builtin_bit_cast(bf16x8, *(const u16x8*)p);
}

// ---------------- prep: x fp32->bf16 convert + both weight transposes (one launch) ----------------
// bx<96: w_qkv [1024][3072] -> wqkvT [3072][1024]; 96<=bx<128: w_proj -> wprojT;
// bx>=128: convert x (slice = (bx-128)*32 + by, 2048 float4 per slice).
__global__ void k_prep(const float* __restrict__ x,
                       const float* __restrict__ wqkv, const float* __restrict__ wproj,
                       unsigned short* __restrict__ xb,
                       unsigned short* __restrict__ wqkvT, unsigned short* __restrict__ wprojT) {
  __shared__ float tile[32][33];
  const int bx = blockIdx.x, by = blockIdx.y;
  const int tx = threadIdx.x, ty = threadIdx.y;   // blockDim (32,8)
  if (bx >= 128) {
    const int slice = (bx - 128) * 32 + by;       // 0..1023
    const int tid = ty * 32 + tx;
    const float4* in4 = (const float4*)x;
    u16x4* out4 = (u16x4*)xb;
#pragma unroll
    for (int j = 0; j < 8; j++) {
      int i = slice * 2048 + j * 256 + tid;
      float4 v = in4[i];
      u16x4 o = { f2bf(v.x), f2bf(v.y), f2bf(v.z), f2bf(v.w) };
      out4[i] = o;
    }
    return;
  }
  const float* in = (bx < 96) ? wqkv : wproj;
  unsigned short* out = (bx < 96) ? wqkvT : wprojT;
  const int Cc = (bx < 96) ? 3072 : 1024;
  const int c0 = ((bx < 96) ? bx : bx - 96) * 32, r0 = by * 32;
#pragma unroll
  for (int j = 0; j < 32; j += 8)
    tile[ty + j][tx] = in[(size_t)(r0 + ty + j) * Cc + c0 + tx];
  __syncthreads();
#pragma unroll
  for (int j = 0; j < 32; j += 8)
    out[(size_t)(c0 + ty + j) * 1024 + r0 + tx] = f2bf(tile[tx][ty + j]);
}

// ---------------- GEMM: C[M x NCOLS] = A[M x 1024] * Bt[NCOLS x 1024]^T ----------------
// 128x128 tile, BK=32, 4 waves each 64x64 (m97 structure; measured 72.6us for NCOLS=3072).
// EPI==1: +bias -> Q (prescaled log2e/8) [B,H,N,D], K [B,H,N,D], V TRANSPOSED [B,H,D,N].
// EPI==2: +bias -> fp32 Out[M x 1024].
template <int EPI, int NCOLS>
__global__ __launch_bounds__(256, 2)
void k_gemm(const unsigned short* __restrict__ A,
            const unsigned short* __restrict__ Bt,
            const float* __restrict__ bias,
            unsigned short* __restrict__ Qp,
            unsigned short* __restrict__ Kp,
            unsigned short* __restrict__ Vtp,
            float* __restrict__ Out) {
  constexpr int K = 1024, NK = K / 32;
  __shared__ unsigned short As[2][128 * 32];
  __shared__ unsigned short Bs[2][128 * 32];

  const int tid = threadIdx.x;
  const int w = tid >> 6, l = tid & 63;
  const int ln = l & 15, kg = l >> 4;
  const int wr = w >> 1, wc = w & 1;

  const int rt = blockIdx.x % (M1 / 128);
  const int ct = blockIdx.x / (M1 / 128);
  const int row0 = rt * 128, col0 = ct * 128;

  f32x4 acc[4][4] = {};

  const unsigned short* Ag = A + (size_t)row0 * K;
  const unsigned short* Bg = Bt + (size_t)col0 * K;

  auto stage = [&](int buf, int kt) {
    const unsigned short* ga = Ag + kt * 32;
    const unsigned short* gb = Bg + kt * 32;
#pragma unroll
    for (int j = 0; j < 2; j++) {
      int c = j * 256 + w * 64 + l;
      int r = c >> 2, s = c & 3;
      int ss = s ^ ((r >> 1) & 3);
      gll16(ga + (size_t)r * K + ss * 8, &As[buf][(j * 256 + w * 64) * 8]);
      gll16(gb + (size_t)r * K + ss * 8, &Bs[buf][(j * 256 + w * 64) * 8]);
    }
  };

  stage(0, 0);
  __syncthreads();

  int buf = 0;
  for (int kt = 0; kt < NK; kt++) {
    if (kt + 1 < NK) stage(buf ^ 1, kt + 1);

    bf16x8 af[4], bfr[4];
#pragma unroll
    for (int m = 0; m < 4; m++) {
      int r = wr * 64 + m * 16 + ln;
      int sl = kg ^ ((r >> 1) & 3);
      af[m] = lds_frag(&As[buf][r * 32 + sl * 8]);
    }
#pragma unroll
    for (int n = 0; n < 4; n++) {
      int r = wc * 64 + n * 16 + ln;
      int sl = kg ^ ((r >> 1) & 3);
      bfr[n] = lds_frag(&Bs[buf][r * 32 + sl * 8]);
    }
    __builtin_amdgcn_s_setprio(1);
#pragma unroll
    for (int m = 0; m < 4; m++)
#pragma unroll
      for (int n = 0; n < 4; n++)
        acc[m][n] = __builtin_amdgcn_mfma_f32_16x16x32_bf16(af[m], bfr[n], acc[m][n], 0, 0, 0);
    __builtin_amdgcn_s_setprio(0);

    __syncthreads();
    buf ^= 1;
  }

  constexpr float QS = 0.18033688011112042f;   // log2(e)/8
  float bv[4];
#pragma unroll
  for (int n = 0; n < 4; n++) bv[n] = bias[col0 + wc * 64 + n * 16 + ln];

  if constexpr (EPI == 1) {
    const int three = col0 >> 10;               // which tensor (Q/K/V)
    const int h = ((col0 & 1023) >> 6) + wc;    // head (64 cols per wave = one head)
    if (three < 2) {
      unsigned short* tgt = (three == 0) ? Qp : Kp;
      const float sc = (three == 0) ? QS : 1.f;
#pragma unroll
      for (int m = 0; m < 4; m++)
#pragma unroll
        for (int r = 0; r < 4; r++) {
          int row = row0 + wr * 64 + m * 16 + kg * 4 + r;
          int bb = row >> 10, nn = row & 1023;
          size_t base = ((size_t)(bb * 16 + h) * 1024 + nn) * 64;
#pragma unroll
          for (int n = 0; n < 4; n++)
            tgt[base + n * 16 + ln] = f2bf((acc[m][n][r] + bv[n]) * sc);
        }
    } else {
      // V transposed -> Vt[bh][d][n]; lines fully dirtied by this wave's adjacent
      // stores -> L2 write-combines (verified round 8: WRITE stayed ~49MB).
#pragma unroll
      for (int m = 0; m < 4; m++)
#pragma unroll
        for (int r = 0; r < 4; r++) {
          int row = row0 + wr * 64 + m * 16 + kg * 4 + r;
          int bb = row >> 10, nn = row & 1023;
          size_t dbase = (size_t)(bb * 16 + h) * 64;
#pragma unroll
          for (int n = 0; n < 4; n++)
            Vtp[(dbase + n * 16 + ln) * 1024 + nn] = f2bf(acc[m][n][r] + bv[n]);
        }
    }
  } else {
#pragma unroll
    for (int m = 0; m < 4; m++)
#pragma unroll
      for (int r = 0; r < 4; r++) {
        int row = row0 + wr * 64 + m * 16 + kg * 4 + r;
#pragma unroll
        for (int n = 0; n < 4; n++)
          Out[(size_t)row * 1024 + col0 + wc * 64 + n * 16 + ln] = acc[m][n][r] + bv[n];
      }
  }
}

// ---------------- flash attention, 32x32x16 swapped MFMA ----------------
// grid (128 bh, 8 q-tiles); 4 waves x 32 q-rows, KVBLK=64, LDS double-buffered.
__global__ __launch_bounds__(256, 4)
void k_attn(const unsigned short* __restrict__ Qg, const unsigned short* __restrict__ Kg,
            const unsigned short* __restrict__ Vtg, unsigned short* __restrict__ AO) {
  __shared__ unsigned short Ks[2][64 * 64];
  __shared__ unsigned short Vs[2][64 * 64];

  const int tid = threadIdx.x;
  const int w = tid >> 6, l = tid & 63;
  const int lq = l & 31, b = l >> 5;

  const int bh = blockIdx.x;
  const int qt = blockIdx.y;
  const int qbase = qt * 128 + w * 32;

  bf16x8 qf[4];
#pragma unroll
  for (int kk = 0; kk < 4; kk++) {
    size_t off = ((size_t)bh * 1024 + qbase + lq) * 64 + kk * 16 + b * 8;
    qf[kk] = __builtin_bit_cast(bf16x8, *(const u16x8*)(Qg + off));
  }

  f32x16 acc[2] = {};
  float mrun = -1e30f, lrun = 0.f;

  const unsigned short* Kbh = Kg + (size_t)bh * 1024 * 64;
  const unsigned short* Vbh = Vtg + (size_t)bh * 64 * 1024;

  auto stage = [&](int buf, int t) {
#pragma unroll
    for (int j = 0; j < 2; j++) {
      int c = j * 256 + w * 64 + l;
      int r = c >> 3, s = c & 7;
      int ss = s ^ (r & 7);
      gll16(Kbh + (size_t)(t * 64 + r) * 64 + ss * 8, &Ks[buf][(j * 256 + w * 64) * 8]);
      gll16(Vbh + (size_t)r * 1024 + t * 64 + ss * 8, &Vs[buf][(j * 256 + w * 64) * 8]);
    }
  };

  stage(0, 0);
  __syncthreads();

  int buf = 0;
  for (int t = 0; t < 16; t++) {
    if (t + 1 < 16) stage(buf ^ 1, t + 1);

    f32x16 s[2];
    __builtin_amdgcn_s_setprio(1);
#pragma unroll
    for (int kb = 0; kb < 2; kb++) {
      f32x16 z = {};
#pragma unroll
      for (int kk = 0; kk < 4; kk++) {
        int row = kb * 32 + lq;
        int ss = (kk * 2 + b) ^ (row & 7);
        bf16x8 kf = lds_frag(&Ks[buf][row * 64 + ss * 8]);
        z = __builtin_amdgcn_mfma_f32_32x32x16_bf16(kf, qf[kk], z, 0, 0, 0);
      }
      s[kb] = z;
    }
    __builtin_amdgcn_s_setprio(0);

    float tm = s[0][0];
#pragma unroll
    for (int kb = 0; kb < 2; kb++)
#pragma unroll
      for (int r = 0; r < 16; r++) tm = fmaxf(tm, s[kb][r]);
    tm = fmaxf(tm, __shfl_xor(tm, 32));

    if (!__all(tm <= mrun + 8.f)) {
      float mnew = fmaxf(mrun, tm);
      float al = fexp2(mrun - mnew);
      mrun = mnew;
      lrun *= al;
#pragma unroll
      for (int r = 0; r < 16; r++) {
        float aq = __shfl(al, (r & 3) + 8 * (r >> 2) + 4 * b);
        acc[0][r] *= aq;
        acc[1][r] *= aq;
      }
    }

    float rs = 0.f;
#pragma unroll
    for (int kb = 0; kb < 2; kb++)
#pragma unroll
      for (int r = 0; r < 16; r++) {
        float pv = fexp2(s[kb][r] - mrun);
        s[kb][r] = pv;
        rs += pv;
      }
    rs += __shfl_xor(rs, 32);
    lrun += rs;

    bf16x8 pa[4];
#pragma unroll
    for (int kb = 0; kb < 2; kb++) {
      u32 pk[4][2];
#pragma unroll
      for (int t4 = 0; t4 < 4; t4++) {
        pk[t4][0] = cvtpk(s[kb][t4 * 4 + 0], s[kb][t4 * 4 + 1]);
        pk[t4][1] = cvtpk(s[kb][t4 * 4 + 2], s[kb][t4 * 4 + 3]);
      }
#pragma unroll
      for (int sh = 0; sh < 2; sh++) {
        u32 a0 = pk[2 * sh][0], b0 = pk[2 * sh + 1][0];
        plswap(a0, b0);
        u32 a1 = pk[2 * sh][1], b1 = pk[2 * sh + 1][1];
        plswap(a1, b1);
        u32x4 fr = { a0, a1, b0, b1 };
        pa[kb * 2 + sh] = __builtin_bit_cast(bf16x8, fr);
      }
    }

    __builtin_amdgcn_s_setprio(1);
#pragma unroll
    for (int n = 0; n < 2; n++) {
#pragma unroll
      for (int st = 0; st < 4; st++) {
        int row = n * 32 + lq;
        int ss = (st * 2 + b) ^ (row & 7);
        bf16x8 vb = lds_frag(&Vs[buf][row * 64 + ss * 8]);
        acc[n] = __builtin_amdgcn_mfma_f32_32x32x16_bf16(pa[st], vb, acc[n], 0, 0, 0);
      }
    }
    __builtin_amdgcn_s_setprio(0);

    __syncthreads();
    buf ^= 1;
  }

  const int bb = bh >> 4, h = bh & 15;
  float linv = 1.f / lrun;
#pragma unroll
  for (int r = 0; r < 16; r++) {
    float lq_r = __shfl(linv, (r & 3) + 8 * (r >> 2) + 4 * b);
    int row = qbase + (r & 3) + 8 * (r >> 2) + 4 * b;
    size_t base = ((size_t)(bb * 1024 + row)) * 1024 + h * 64;
#pragma unroll
    for (int n = 0; n < 2; n++)
      AO[base + n * 32 + lq] = f2bf(acc[n][r] * lq_r);
  }
}

// ---------------- launch ----------------
extern "C" void kernel_launch(void* const* d_in, const int* in_sizes, int n_in,
                              void* d_out, int out_size, void* d_ws, size_t ws_size,
                              hipStream_t stream) {
  const float* x      = (const float*)d_in[0];
  const float* w_qkv  = (const float*)d_in[1];
  const float* b_qkv  = (const float*)d_in[2];
  const float* w_proj = (const float*)d_in[3];
  const float* b_proj = (const float*)d_in[4];
  float* out = (float*)d_out;

  constexpr size_t SZ_XB  = (size_t)8192 * 1024 * 2;
  constexpr size_t SZ_WQ  = (size_t)3072 * 1024 * 2;
  constexpr size_t SZ_WP  = (size_t)1024 * 1024 * 2;
  constexpr size_t SZ_QKV = (size_t)8 * 16 * 1024 * 64 * 2;
  char* ws = (char*)d_ws;
  unsigned short* xb     = (unsigned short*)(ws);
  unsigned short* wqkvT  = (unsigned short*)(ws + SZ_XB);
  unsigned short* wprojT = (unsigned short*)(ws + SZ_XB + SZ_WQ);
  unsigned short* Qb     = (unsigned short*)(ws + SZ_XB + SZ_WQ + SZ_WP);
  unsigned short* Kb     = (unsigned short*)(ws + SZ_XB + SZ_WQ + SZ_WP + SZ_QKV);
  unsigned short* Vtb    = (unsigned short*)(ws + SZ_XB + SZ_WQ + SZ_WP + 2 * SZ_QKV);
  unsigned short* AOb    = (unsigned short*)(ws + SZ_XB + SZ_WQ + SZ_WP + 3 * SZ_QKV);
  size_t needed = SZ_XB + SZ_WQ + SZ_WP + 4 * SZ_QKV;   // ~92.3 MB
  if (ws_size < needed) return;

  // 1) x convert + weight transposes (one launch)
  k_prep<<<dim3(160, 32), dim3(32, 8), 0, stream>>>(x, w_qkv, w_proj, xb, wqkvT, wprojT);
  // 2) QKV GEMM -> Q(scaled), K [B,H,N,D]; V written transposed -> Vt [B,H,D,N]
  k_gemm<1, 3072><<<64 * 24, 256, 0, stream>>>(xb, wqkvT, b_qkv, Qb, Kb, Vtb, nullptr);
  // 3) flash attention -> AO
  k_attn<<<dim3(128, 8), 256, 0, stream>>>(Qb, Kb, Vtb, AOb);
  // 4) projection -> out fp32
  k_gemm<2, 1024><<<64 * 8, 256, 0, stream>>>(AOb, wprojT, b_proj, nullptr, nullptr, nullptr, out);
}